// Round 8
// baseline (1390.084 us; speedup 1.0000x reference)
//
#include <hip/hip_runtime.h>

#define HWN 16384
#define WDIM 128

typedef __bf16 bf16x8 __attribute__((ext_vector_type(8)));
typedef __bf16 bf16x4 __attribute__((ext_vector_type(4)));
typedef __bf16 bf16x2 __attribute__((ext_vector_type(2)));
typedef float floatx4 __attribute__((ext_vector_type(4)));

#define LSTR 36  // LDS row stride in bf16 (32+4 pad)

// ---------- GEMM: C[M,16384] = (Ah+Al)[M,K] x (Bh+Bl)[K,16384], split bf16, fp32-quality ----------
// 128x128 tile, BK=32, 4 waves (2x2 quadrants of 64x64), 3 MFMA products.
__global__ __launch_bounds__(256, 2) void gemm_bf3(
    const __bf16* __restrict__ Ah, const __bf16* __restrict__ Al,
    const __bf16* __restrict__ Bh, const __bf16* __restrict__ Bl,
    float* __restrict__ C, int K, long sA, long sB, long sC) {
  __shared__ __bf16 sAh[128 * LSTR], sAl[128 * LSTR], sBh[128 * LSTR], sBl[128 * LSTR];
  const int bz = blockIdx.z;
  Ah += (long)bz * sA;
  Al += (long)bz * sA;
  Bh += (long)bz * sB;
  Bl += (long)bz * sB;
  C += (long)bz * sC;
  const int tid = threadIdx.x;
  const int n0 = blockIdx.x << 7, m0 = blockIdx.y << 7;
  const int arow = tid >> 1, akq = (tid & 1) << 4;
  const int bn = (tid & 63) << 1;
  const int bkb = (tid >> 6) << 3;
  const int lane = tid & 63, wv = tid >> 6;
  const int mq = (wv & 1) << 6, nq = (wv >> 1) << 6;
  const int fm = lane & 15, fq = lane >> 4;
  floatx4 acc[4][4] = {};
  for (int k0 = 0; k0 < K; k0 += 32) {
    const __bf16* pAh = Ah + (long)(m0 + arow) * K + k0 + akq;
    const __bf16* pAl = Al + (long)(m0 + arow) * K + k0 + akq;
    bf16x8 a0 = *(const bf16x8*)pAh;
    bf16x8 a1 = *(const bf16x8*)(pAh + 8);
    bf16x8 a2 = *(const bf16x8*)pAl;
    bf16x8 a3 = *(const bf16x8*)(pAl + 8);
    const __bf16* pBh = Bh + (long)(k0 + bkb) * HWN + n0 + bn;
    const __bf16* pBl = Bl + (long)(k0 + bkb) * HWN + n0 + bn;
    bf16x2 vh[8], vl[8];
#pragma unroll
    for (int r = 0; r < 8; ++r) {
      vh[r] = *(const bf16x2*)(pBh + (long)r * HWN);
      vl[r] = *(const bf16x2*)(pBl + (long)r * HWN);
    }
    bf16x8 bh0, bh1, bl0, bl1;
#pragma unroll
    for (int r = 0; r < 8; ++r) {
      bh0[r] = vh[r][0];
      bh1[r] = vh[r][1];
      bl0[r] = vl[r][0];
      bl1[r] = vl[r][1];
    }
    __syncthreads();
    *(bf16x8*)&sAh[arow * LSTR + akq] = a0;
    *(bf16x8*)&sAh[arow * LSTR + akq + 8] = a1;
    *(bf16x8*)&sAl[arow * LSTR + akq] = a2;
    *(bf16x8*)&sAl[arow * LSTR + akq + 8] = a3;
    *(bf16x8*)&sBh[bn * LSTR + bkb] = bh0;
    *(bf16x8*)&sBh[(bn + 1) * LSTR + bkb] = bh1;
    *(bf16x8*)&sBl[bn * LSTR + bkb] = bl0;
    *(bf16x8*)&sBl[(bn + 1) * LSTR + bkb] = bl1;
    __syncthreads();
    bf16x8 fAh[4], fAl[4];
#pragma unroll
    for (int i = 0; i < 4; ++i) {
      fAh[i] = *(const bf16x8*)&sAh[(mq + i * 16 + fm) * LSTR + fq * 8];
      fAl[i] = *(const bf16x8*)&sAl[(mq + i * 16 + fm) * LSTR + fq * 8];
    }
#pragma unroll
    for (int j = 0; j < 4; ++j) {
      bf16x8 bh = *(const bf16x8*)&sBh[(nq + j * 16 + fm) * LSTR + fq * 8];
      bf16x8 bl = *(const bf16x8*)&sBl[(nq + j * 16 + fm) * LSTR + fq * 8];
#pragma unroll
      for (int i = 0; i < 4; ++i) {
        acc[i][j] = __builtin_amdgcn_mfma_f32_16x16x32_bf16(fAh[i], bh, acc[i][j], 0, 0, 0);
        acc[i][j] = __builtin_amdgcn_mfma_f32_16x16x32_bf16(fAl[i], bh, acc[i][j], 0, 0, 0);
        acc[i][j] = __builtin_amdgcn_mfma_f32_16x16x32_bf16(fAh[i], bl, acc[i][j], 0, 0, 0);
      }
    }
  }
#pragma unroll
  for (int i = 0; i < 4; ++i)
#pragma unroll
    for (int j = 0; j < 4; ++j) {
      const int col = n0 + nq + j * 16 + fm;
#pragma unroll
      for (int r = 0; r < 4; ++r) {
        const int row = m0 + mq + i * 16 + fq * 4 + r;
        C[(long)row * HWN + col] = acc[i][j][r];
      }
    }
}

// ---------- split fp32 -> bf16 hi/lo (scalar, for weights) ----------
__global__ __launch_bounds__(256) void split_w(
    const float* __restrict__ w, __bf16* __restrict__ hi, __bf16* __restrict__ lo, int n) {
  int i = blockIdx.x * 256 + threadIdx.x;
  if (i < n) {
    float v = w[i];
    __bf16 h = (__bf16)v;
    hi[i] = h;
    lo[i] = (__bf16)(v - (float)h);
  }
}

// ---------- split_x: vectorized fp32 -> bf16 hi/lo (float4 in, bf16x4 out x2) ----------
__global__ __launch_bounds__(256) void split_x(
    const float* __restrict__ w, __bf16* __restrict__ hi, __bf16* __restrict__ lo, long n4) {
  long i = (long)blockIdx.x * 256 + threadIdx.x;
  if (i < n4) {
    float4 v = *(const float4*)(w + i * 4);
    bf16x4 h4, l4;
    __bf16 h0 = (__bf16)v.x, h1 = (__bf16)v.y, h2 = (__bf16)v.z, h3 = (__bf16)v.w;
    h4[0] = h0; h4[1] = h1; h4[2] = h2; h4[3] = h3;
    l4[0] = (__bf16)(v.x - (float)h0);
    l4[1] = (__bf16)(v.y - (float)h1);
    l4[2] = (__bf16)(v.z - (float)h2);
    l4[3] = (__bf16)(v.w - (float)h3);
    *(bf16x4*)&hi[i * 4] = h4;
    *(bf16x4*)&lo[i * 4] = l4;
  }
}

// ---------- dw_split: depthwise 3x3 on all 1152 ch, output bf16 hi/lo, q/k sumsq fused ----------
__global__ __launch_bounds__(256) void dw_split(
    const float* __restrict__ qkv1, const float* __restrict__ dww,
    __bf16* __restrict__ dwh, __bf16* __restrict__ dwl,
    float* __restrict__ qs, float* __restrict__ ks, int b0) {
  const int tid = threadIdx.x;
  const int ch = blockIdx.x;
  const int yh = blockIdx.y;
  const int bz = blockIdx.z;
  const int xg = tid & 31;
  const int rg = tid >> 5;
  const float4* P = (const float4*)(qkv1 + ((long)bz * 1152 + ch) * HWN);
  const float* wp = dww + (long)ch * 9;
  const float w00 = wp[0], w01 = wp[1], w02 = wp[2];
  const float w10 = wp[3], w11 = wp[4], w12 = wp[5];
  const float w20 = wp[6], w21 = wp[7], w22 = wp[8];
  const int y0 = (yh << 6) + (rg << 3);
  float4 vr[10];
#pragma unroll
  for (int r = 0; r < 10; ++r) {
    int yy = y0 - 1 + r;
    vr[r] = make_float4(0.f, 0.f, 0.f, 0.f);
    if (yy >= 0 && yy < WDIM) vr[r] = P[yy * 32 + xg];
  }
  float lf[10], rt[10];
#pragma unroll
  for (int r = 0; r < 10; ++r) {
    float l_ = __shfl_up(vr[r].w, 1, 64);
    float r_ = __shfl_down(vr[r].x, 1, 64);
    lf[r] = (xg == 0) ? 0.f : l_;
    rt[r] = (xg == 31) ? 0.f : r_;
  }
  const long obase = ((long)bz * 1152 + ch) * HWN;
  float sq = 0.f;
#pragma unroll
  for (int i = 0; i < 8; ++i) {
    const float t0 = lf[i], t1 = vr[i].x, t2 = vr[i].y, t3 = vr[i].z, t4 = vr[i].w, t5 = rt[i];
    const float m0_ = lf[i + 1], m1 = vr[i + 1].x, m2 = vr[i + 1].y, m3 = vr[i + 1].z,
                m4 = vr[i + 1].w, m5 = rt[i + 1];
    const float b0_ = lf[i + 2], b1 = vr[i + 2].x, b2 = vr[i + 2].y, b3 = vr[i + 2].z,
                b4 = vr[i + 2].w, b5 = rt[i + 2];
    float o0 = w00 * t0 + w01 * t1 + w02 * t2 + w10 * m0_ + w11 * m1 + w12 * m2 +
               w20 * b0_ + w21 * b1 + w22 * b2;
    float o1 = w00 * t1 + w01 * t2 + w02 * t3 + w10 * m1 + w11 * m2 + w12 * m3 +
               w20 * b1 + w21 * b2 + w22 * b3;
    float o2 = w00 * t2 + w01 * t3 + w02 * t4 + w10 * m2 + w11 * m3 + w12 * m4 +
               w20 * b2 + w21 * b3 + w22 * b4;
    float o3 = w00 * t3 + w01 * t4 + w02 * t5 + w10 * m3 + w11 * m4 + w12 * m5 +
               w20 * b3 + w21 * b4 + w22 * b5;
    sq += o0 * o0 + o1 * o1 + o2 * o2 + o3 * o3;
    bf16x4 h4, l4;
    __bf16 h0 = (__bf16)o0, h1 = (__bf16)o1, h2 = (__bf16)o2, h3 = (__bf16)o3;
    h4[0] = h0; h4[1] = h1; h4[2] = h2; h4[3] = h3;
    l4[0] = (__bf16)(o0 - (float)h0);
    l4[1] = (__bf16)(o1 - (float)h1);
    l4[2] = (__bf16)(o2 - (float)h2);
    l4[3] = (__bf16)(o3 - (float)h3);
    long off = obase + (y0 + i) * WDIM + xg * 4;
    *(bf16x4*)&dwh[off] = h4;
    *(bf16x4*)&dwl[off] = l4;
  }
  if (ch < 768) {
#pragma unroll
    for (int off = 32; off >= 1; off >>= 1) sq += __shfl_down(sq, off, 64);
    if ((tid & 63) == 0) {
      int b = b0 + bz;
      if (ch < 384)
        atomicAdd(qs + b * 384 + ch, sq);
      else
        atomicAdd(ks + b * 384 + (ch - 384), sq);
    }
  }
}

// ---------- gram_mfma: G[b,h] += Qd(48,P) x Kd(48,P)^T via 16x16x32 MFMA (split bf16) ----------
// Grid (32 px-chunks, 8 h, nbc), 256 thr = 4 waves; wave w owns px [pc*512 + w*128, +128).
__global__ __launch_bounds__(256) void gram_mfma(
    const __bf16* __restrict__ dwh, const __bf16* __restrict__ dwl,
    float* __restrict__ gram, int b0) {
  __shared__ float R[4][2304];
  const int tid = threadIdx.x, lane = tid & 63, wv = tid >> 6;
  const int pc = blockIdx.x, h = blockIdx.y, bz = blockIdx.z;
  const __bf16* Qh = dwh + ((long)bz * 1152 + h * 48) * HWN;
  const __bf16* Ql = dwl + ((long)bz * 1152 + h * 48) * HWN;
  const __bf16* Kh = dwh + ((long)bz * 1152 + 384 + h * 48) * HWN;
  const __bf16* Kl = dwl + ((long)bz * 1152 + 384 + h * 48) * HWN;
  const int fm = lane & 15;
  const int fk = (lane >> 4) << 3;
  floatx4 acc[3][3] = {};
  const int pstart = pc * 512 + wv * 128;
  for (int p0 = pstart; p0 < pstart + 128; p0 += 32) {
    bf16x8 ah[3], al[3], bh[3], bl[3];
#pragma unroll
    for (int i = 0; i < 3; ++i) {
      const long ro = (long)(i * 16 + fm) * HWN + p0 + fk;
      ah[i] = *(const bf16x8*)(Qh + ro);
      al[i] = *(const bf16x8*)(Ql + ro);
      bh[i] = *(const bf16x8*)(Kh + ro);
      bl[i] = *(const bf16x8*)(Kl + ro);
    }
#pragma unroll
    for (int i = 0; i < 3; ++i)
#pragma unroll
      for (int j = 0; j < 3; ++j) {
        acc[i][j] = __builtin_amdgcn_mfma_f32_16x16x32_bf16(ah[i], bh[j], acc[i][j], 0, 0, 0);
        acc[i][j] = __builtin_amdgcn_mfma_f32_16x16x32_bf16(al[i], bh[j], acc[i][j], 0, 0, 0);
        acc[i][j] = __builtin_amdgcn_mfma_f32_16x16x32_bf16(ah[i], bl[j], acc[i][j], 0, 0, 0);
      }
  }
#pragma unroll
  for (int i = 0; i < 3; ++i)
#pragma unroll
    for (int j = 0; j < 3; ++j)
#pragma unroll
      for (int r = 0; r < 4; ++r)
        R[wv][(i * 16 + (lane >> 4) * 4 + r) * 48 + j * 16 + fm] = acc[i][j][r];
  __syncthreads();
  float* gb = gram + (long)((b0 + bz) * 8 + h) * 2304;
  for (int idx = tid; idx < 2304; idx += 256) {
    float s = R[0][idx] + R[1][idx] + R[2][idx] + R[3][idx];
    atomicAdd(gb + idx, s);
  }
}

// ---------- attn_M: normalize+top7+softmax then M = proj_w @ blockdiag(attn) ----------
__global__ __launch_bounds__(256) void attn_M(
    const float* __restrict__ gram, const float* __restrict__ qs, const float* __restrict__ ks,
    const float* __restrict__ temp, const float* __restrict__ pw,
    __bf16* __restrict__ Mh, __bf16* __restrict__ Ml, int b0) {
  const int z = blockIdx.x;
  const int b = b0 + (z >> 3), h = z & 7;
  __shared__ float kn[48];
  __shared__ float at[48][49];
  const int tid = threadIdx.x;
  if (tid < 48) kn[tid] = fmaxf(sqrtf(ks[b * 384 + h * 48 + tid]), 1e-12f);
  __syncthreads();
  if (tid < 48) {
    const int c = tid;
    float qn = fmaxf(sqrtf(qs[b * 384 + h * 48 + c]), 1e-12f);
    float tv = temp[h];
    const float* gr = gram + (long)(b * 8 + h) * 2304 + c * 48;
    float s[48];
#pragma unroll
    for (int d = 0; d < 48; ++d) s[d] = gr[d] / (qn * kn[d]) * tv;
    unsigned long long sel = 0ull;
    float m0 = 0.f;
    for (int it = 0; it < 7; ++it) {
      float mx = -3.0e38f;
      int mi = 0;
#pragma unroll
      for (int d = 0; d < 48; ++d) {
        bool taken = (sel >> d) & 1ull;
        if (!taken && s[d] > mx) { mx = s[d]; mi = d; }
      }
      sel |= (1ull << mi);
      if (it == 0) m0 = mx;
    }
    float sum = 0.f;
    float e[48];
#pragma unroll
    for (int d = 0; d < 48; ++d) {
      bool t = (sel >> d) & 1ull;
      float ev = t ? expf(s[d] - m0) : 0.f;
      e[d] = ev;
      sum += ev;
    }
    float inv = 1.f / sum;
#pragma unroll
    for (int d = 0; d < 48; ++d) at[c][d] = e[d] * inv;
  }
  __syncthreads();
  for (int idx = tid; idx < 384 * 48; idx += 256) {
    int o = idx / 48, d = idx % 48;
    const float* pr = pw + (long)o * 384 + h * 48;
    float acc = 0.f;
#pragma unroll
    for (int c = 0; c < 48; ++c) acc += pr[c] * at[c][d];
    long oi = ((long)b * 384 + o) * 384 + h * 48 + d;
    __bf16 hh = (__bf16)acc;
    Mh[oi] = hh;
    Ml[oi] = (__bf16)(acc - (float)hh);
  }
}

extern "C" void kernel_launch(void* const* d_in, const int* in_sizes, int n_in,
                              void* d_out, int out_size, void* d_ws, size_t ws_size,
                              hipStream_t stream) {
  const float* x = (const float*)d_in[0];       // (8,384,128,128)
  const float* qkv_w = (const float*)d_in[1];   // (1152,384)
  const float* dw_w = (const float*)d_in[2];    // (1152,1,3,3)
  const float* proj_w = (const float*)d_in[3];  // (384,384)
  const float* temp = (const float*)d_in[4];    // (8,)
  float* out = (float*)d_out;
  float* ws = (float*)d_ws;

  // ws layout (floats):
  float* gram = ws;                        // 147456
  float* qs = gram + 147456;               // 3072
  float* ks = qs + 3072;                   // 3072
  __bf16* Wh = (__bf16*)(ks + 3072);       // 442368 bf16
  __bf16* Wl = Wh + 442368;                // 442368 bf16
  __bf16* Mh = Wl + 442368;                // 8*147456 bf16
  __bf16* Ml = Mh + 1179648;               // 8*147456 bf16
  float* qkv1 = (float*)(Ml + 1179648);    // nb*1152*16384 f
  const long SMALLS = 1775616L;            // floats
  // per-batch: qkv1 fp32 (18874368) + dwh/dwl bf16 (18874368 f) + Xh/Xl bf16 (6291456 f)
  const long PERB = 44040192L;
  long wsf = (long)(ws_size / 4);
  int nb = (int)((wsf - SMALLS) / PERB);
  if (nb < 1) nb = 1;
  if (nb > 8) nb = 8;
  __bf16* dwh = (__bf16*)(qkv1 + (long)nb * 18874368L);
  __bf16* dwl = dwh + (long)nb * 18874368L;
  __bf16* Xh = dwl + (long)nb * 18874368L;
  __bf16* Xl = Xh + (long)nb * 6291456L;

  hipMemsetAsync(gram, 0, (147456 + 3072 + 3072) * sizeof(float), stream);
  split_w<<<dim3((442368 + 255) / 256), 256, 0, stream>>>(qkv_w, Wh, Wl, 442368);

  for (int b0 = 0; b0 < 8; b0 += nb) {
    int nbc = (8 - b0 < nb) ? (8 - b0) : nb;
    // pre-split x chunk -> Xh/Xl (bf16 hi/lo), vectorized
    split_x<<<dim3(nbc * 6144), 256, 0, stream>>>(
        x + (long)b0 * 6291456L, Xh, Xl, (long)nbc * 1572864L);
    // K1: qkv1 = W @ x[b]  (M=1152, K=384), all-bf16 split GEMM
    gemm_bf3<<<dim3(128, 9, nbc), 256, 0, stream>>>(
        Wh, Wl, Xh, Xl, qkv1, 384, 0L, 6291456L, 18874368L);
    // dw all 1152 channels -> bf16 hi/lo, q/k sumsq fused
    dw_split<<<dim3(1152, 2, nbc), 256, 0, stream>>>(qkv1, dw_w, dwh, dwl, qs, ks, b0);
    // gram via MFMA on split outputs (32 px-chunks for occupancy)
    gram_mfma<<<dim3(32, 8, nbc), 256, 0, stream>>>(dwh, dwl, gram, b0);
    // attn + M build (fused)
    attn_M<<<dim3(nbc * 8), 256, 0, stream>>>(gram, qs, ks, temp, proj_w, Mh, Ml, b0);
    // K5: out[b] = M_b @ v[b]  (M=384, K=384), pre-split bf16 B (v = dw channels 768..1151)
    gemm_bf3<<<dim3(128, 3, nbc), 256, 0, stream>>>(
        Mh + (long)b0 * 147456L, Ml + (long)b0 * 147456L,
        dwh + 768L * HWN, dwl + 768L * HWN,
        out + (long)b0 * 6291456L, 384, 147456L, 18874368L, 6291456L);
  }
}

// Round 11
// 1320.664 us; speedup vs baseline: 1.0526x; 1.0526x over previous
//
#include <hip/hip_runtime.h>

#define HWN 16384
#define WDIM 128

typedef __bf16 bf16x8 __attribute__((ext_vector_type(8)));
typedef __bf16 bf16x4 __attribute__((ext_vector_type(4)));
typedef __bf16 bf16x2 __attribute__((ext_vector_type(2)));
typedef float floatx4 __attribute__((ext_vector_type(4)));

#define LSTR 36  // LDS row stride in bf16 (32+4 pad)

// ---------- K1 GEMM: C[M,16384] = (Ah+Al)[M,K] x split(B fp32)[K,16384] ----------
// At the 2-barrier structural ceiling (~870 TF measured) — do not touch.
__global__ __launch_bounds__(256, 2) void gemm_mfma3(
    const __bf16* __restrict__ Ah, const __bf16* __restrict__ Al,
    const float* __restrict__ B, float* __restrict__ C,
    int K, long sA, long sB, long sC) {
  __shared__ __bf16 sAh[128 * LSTR], sAl[128 * LSTR], sBh[128 * LSTR], sBl[128 * LSTR];
  const int bz = blockIdx.z;
  Ah += (long)bz * sA;
  Al += (long)bz * sA;
  B += (long)bz * sB;
  C += (long)bz * sC;
  const int tid = threadIdx.x;
  const int n0 = blockIdx.x << 7, m0 = blockIdx.y << 7;
  const int arow = tid >> 1, akq = (tid & 1) << 4;
  const int bn = (tid & 63) << 1;
  const int bkb = (tid >> 6) << 3;
  const int lane = tid & 63, wv = tid >> 6;
  const int mq = (wv & 1) << 6, nq = (wv >> 1) << 6;
  const int fm = lane & 15, fq = lane >> 4;
  floatx4 acc[4][4] = {};
  for (int k0 = 0; k0 < K; k0 += 32) {
    const __bf16* pAh = Ah + (long)(m0 + arow) * K + k0 + akq;
    const __bf16* pAl = Al + (long)(m0 + arow) * K + k0 + akq;
    bf16x8 a0 = *(const bf16x8*)pAh;
    bf16x8 a1 = *(const bf16x8*)(pAh + 8);
    bf16x8 a2 = *(const bf16x8*)pAl;
    bf16x8 a3 = *(const bf16x8*)(pAl + 8);
    const float* pB = B + (long)(k0 + bkb) * HWN + n0 + bn;
    float2 v[8];
#pragma unroll
    for (int r = 0; r < 8; ++r) v[r] = *(const float2*)(pB + (long)r * HWN);
    bf16x8 bh0, bh1, bl0, bl1;
#pragma unroll
    for (int r = 0; r < 8; ++r) {
      float vx = v[r].x, vy = v[r].y;
      __bf16 hx = (__bf16)vx, hy = (__bf16)vy;
      bh0[r] = hx;
      bh1[r] = hy;
      bl0[r] = (__bf16)(vx - (float)hx);
      bl1[r] = (__bf16)(vy - (float)hy);
    }
    __syncthreads();
    *(bf16x8*)&sAh[arow * LSTR + akq] = a0;
    *(bf16x8*)&sAh[arow * LSTR + akq + 8] = a1;
    *(bf16x8*)&sAl[arow * LSTR + akq] = a2;
    *(bf16x8*)&sAl[arow * LSTR + akq + 8] = a3;
    *(bf16x8*)&sBh[bn * LSTR + bkb] = bh0;
    *(bf16x8*)&sBh[(bn + 1) * LSTR + bkb] = bh1;
    *(bf16x8*)&sBl[bn * LSTR + bkb] = bl0;
    *(bf16x8*)&sBl[(bn + 1) * LSTR + bkb] = bl1;
    __syncthreads();
    bf16x8 fAh[4], fAl[4];
#pragma unroll
    for (int i = 0; i < 4; ++i) {
      fAh[i] = *(const bf16x8*)&sAh[(mq + i * 16 + fm) * LSTR + fq * 8];
      fAl[i] = *(const bf16x8*)&sAl[(mq + i * 16 + fm) * LSTR + fq * 8];
    }
#pragma unroll
    for (int j = 0; j < 4; ++j) {
      bf16x8 bh = *(const bf16x8*)&sBh[(nq + j * 16 + fm) * LSTR + fq * 8];
      bf16x8 bl = *(const bf16x8*)&sBl[(nq + j * 16 + fm) * LSTR + fq * 8];
#pragma unroll
      for (int i = 0; i < 4; ++i) {
        acc[i][j] = __builtin_amdgcn_mfma_f32_16x16x32_bf16(fAh[i], bh, acc[i][j], 0, 0, 0);
        acc[i][j] = __builtin_amdgcn_mfma_f32_16x16x32_bf16(fAl[i], bh, acc[i][j], 0, 0, 0);
        acc[i][j] = __builtin_amdgcn_mfma_f32_16x16x32_bf16(fAh[i], bl, acc[i][j], 0, 0, 0);
      }
    }
  }
#pragma unroll
  for (int i = 0; i < 4; ++i)
#pragma unroll
    for (int j = 0; j < 4; ++j) {
      const int col = n0 + nq + j * 16 + fm;
#pragma unroll
      for (int r = 0; r < 4; ++r) {
        const int row = m0 + mq + i * 16 + fq * 4 + r;
        C[(long)row * HWN + col] = acc[i][j][r];
      }
    }
}

// ---------- K5 GEMM: same structure, B pre-split bf16 (hi/lo arrays) ----------
__global__ __launch_bounds__(256, 2) void gemm_bf3(
    const __bf16* __restrict__ Ah, const __bf16* __restrict__ Al,
    const __bf16* __restrict__ Bh, const __bf16* __restrict__ Bl,
    float* __restrict__ C, int K, long sA, long sB, long sC) {
  __shared__ __bf16 sAh[128 * LSTR], sAl[128 * LSTR], sBh[128 * LSTR], sBl[128 * LSTR];
  const int bz = blockIdx.z;
  Ah += (long)bz * sA;
  Al += (long)bz * sA;
  Bh += (long)bz * sB;
  Bl += (long)bz * sB;
  C += (long)bz * sC;
  const int tid = threadIdx.x;
  const int n0 = blockIdx.x << 7, m0 = blockIdx.y << 7;
  const int arow = tid >> 1, akq = (tid & 1) << 4;
  const int bn = (tid & 63) << 1;
  const int bkb = (tid >> 6) << 3;
  const int lane = tid & 63, wv = tid >> 6;
  const int mq = (wv & 1) << 6, nq = (wv >> 1) << 6;
  const int fm = lane & 15, fq = lane >> 4;
  floatx4 acc[4][4] = {};
  for (int k0 = 0; k0 < K; k0 += 32) {
    const __bf16* pAh = Ah + (long)(m0 + arow) * K + k0 + akq;
    const __bf16* pAl = Al + (long)(m0 + arow) * K + k0 + akq;
    bf16x8 a0 = *(const bf16x8*)pAh;
    bf16x8 a1 = *(const bf16x8*)(pAh + 8);
    bf16x8 a2 = *(const bf16x8*)pAl;
    bf16x8 a3 = *(const bf16x8*)(pAl + 8);
    const __bf16* pBh = Bh + (long)(k0 + bkb) * HWN + n0 + bn;
    const __bf16* pBl = Bl + (long)(k0 + bkb) * HWN + n0 + bn;
    bf16x2 vh[8], vl[8];
#pragma unroll
    for (int r = 0; r < 8; ++r) {
      vh[r] = *(const bf16x2*)(pBh + (long)r * HWN);
      vl[r] = *(const bf16x2*)(pBl + (long)r * HWN);
    }
    bf16x8 bh0, bh1, bl0, bl1;
#pragma unroll
    for (int r = 0; r < 8; ++r) {
      bh0[r] = vh[r][0];
      bh1[r] = vh[r][1];
      bl0[r] = vl[r][0];
      bl1[r] = vl[r][1];
    }
    __syncthreads();
    *(bf16x8*)&sAh[arow * LSTR + akq] = a0;
    *(bf16x8*)&sAh[arow * LSTR + akq + 8] = a1;
    *(bf16x8*)&sAl[arow * LSTR + akq] = a2;
    *(bf16x8*)&sAl[arow * LSTR + akq + 8] = a3;
    *(bf16x8*)&sBh[bn * LSTR + bkb] = bh0;
    *(bf16x8*)&sBh[(bn + 1) * LSTR + bkb] = bh1;
    *(bf16x8*)&sBl[bn * LSTR + bkb] = bl0;
    *(bf16x8*)&sBl[(bn + 1) * LSTR + bkb] = bl1;
    __syncthreads();
    bf16x8 fAh[4], fAl[4];
#pragma unroll
    for (int i = 0; i < 4; ++i) {
      fAh[i] = *(const bf16x8*)&sAh[(mq + i * 16 + fm) * LSTR + fq * 8];
      fAl[i] = *(const bf16x8*)&sAl[(mq + i * 16 + fm) * LSTR + fq * 8];
    }
#pragma unroll
    for (int j = 0; j < 4; ++j) {
      bf16x8 bh = *(const bf16x8*)&sBh[(nq + j * 16 + fm) * LSTR + fq * 8];
      bf16x8 bl = *(const bf16x8*)&sBl[(nq + j * 16 + fm) * LSTR + fq * 8];
#pragma unroll
      for (int i = 0; i < 4; ++i) {
        acc[i][j] = __builtin_amdgcn_mfma_f32_16x16x32_bf16(fAh[i], bh, acc[i][j], 0, 0, 0);
        acc[i][j] = __builtin_amdgcn_mfma_f32_16x16x32_bf16(fAl[i], bh, acc[i][j], 0, 0, 0);
        acc[i][j] = __builtin_amdgcn_mfma_f32_16x16x32_bf16(fAh[i], bl, acc[i][j], 0, 0, 0);
      }
    }
  }
#pragma unroll
  for (int i = 0; i < 4; ++i)
#pragma unroll
    for (int j = 0; j < 4; ++j) {
      const int col = n0 + nq + j * 16 + fm;
#pragma unroll
      for (int r = 0; r < 4; ++r) {
        const int row = m0 + mq + i * 16 + fq * 4 + r;
        C[(long)row * HWN + col] = acc[i][j][r];
      }
    }
}

// ---------- split fp32 -> bf16 hi/lo ----------
__global__ __launch_bounds__(256) void split_w(
    const float* __restrict__ w, __bf16* __restrict__ hi, __bf16* __restrict__ lo, int n) {
  int i = blockIdx.x * 256 + threadIdx.x;
  if (i < n) {
    float v = w[i];
    __bf16 h = (__bf16)v;
    hi[i] = h;
    lo[i] = (__bf16)(v - (float)h);
  }
}

// ---------- dw_split: depthwise 3x3, full-height strips, 18-deep burst loads ----------
// Block = (channel, batch). 256 thr: xg=tid&31 (4-px col group), rg=tid>>5 (16-row strip).
// All 18 input rows loaded up-front (deep vmcnt pipeline); rolling 3-row halo window.
__global__ __launch_bounds__(256) void dw_split(
    const float* __restrict__ qkv1, const float* __restrict__ dww,
    __bf16* __restrict__ dwh, __bf16* __restrict__ dwl,
    float* __restrict__ qs, float* __restrict__ ks, int b0) {
  const int tid = threadIdx.x;
  const int ch = blockIdx.x;
  const int bz = blockIdx.y;
  const int xg = tid & 31;
  const int rg = tid >> 5;
  const float4* P = (const float4*)(qkv1 + ((long)bz * 1152 + ch) * HWN);
  const float* wp = dww + (long)ch * 9;
  const float w00 = wp[0], w01 = wp[1], w02 = wp[2];
  const float w10 = wp[3], w11 = wp[4], w12 = wp[5];
  const float w20 = wp[6], w21 = wp[7], w22 = wp[8];
  const int y0 = rg << 4;
  float4 vr[18];
#pragma unroll
  for (int r = 0; r < 18; ++r) {
    int yy = y0 - 1 + r;
    vr[r] = make_float4(0.f, 0.f, 0.f, 0.f);
    if (yy >= 0 && yy < WDIM) vr[r] = P[yy * 32 + xg];
  }
  // rolling halo window: lA/rA = row i, lB/rB = row i+1, lC/rC = row i+2
  float lA = __shfl_up(vr[0].w, 1, 64);
  float rA = __shfl_down(vr[0].x, 1, 64);
  if (xg == 0) lA = 0.f;
  if (xg == 31) rA = 0.f;
  float lB = __shfl_up(vr[1].w, 1, 64);
  float rB = __shfl_down(vr[1].x, 1, 64);
  if (xg == 0) lB = 0.f;
  if (xg == 31) rB = 0.f;
  const long obase = ((long)bz * 1152 + ch) * HWN;
  float sq = 0.f;
#pragma unroll
  for (int i = 0; i < 16; ++i) {
    float lC = __shfl_up(vr[i + 2].w, 1, 64);
    float rC = __shfl_down(vr[i + 2].x, 1, 64);
    if (xg == 0) lC = 0.f;
    if (xg == 31) rC = 0.f;
    const float t0 = lA, t1 = vr[i].x, t2 = vr[i].y, t3 = vr[i].z, t4 = vr[i].w, t5 = rA;
    const float m0_ = lB, m1 = vr[i + 1].x, m2 = vr[i + 1].y, m3 = vr[i + 1].z,
                m4 = vr[i + 1].w, m5 = rB;
    const float b0_ = lC, b1 = vr[i + 2].x, b2 = vr[i + 2].y, b3 = vr[i + 2].z,
                b4 = vr[i + 2].w, b5 = rC;
    float o0 = w00 * t0 + w01 * t1 + w02 * t2 + w10 * m0_ + w11 * m1 + w12 * m2 +
               w20 * b0_ + w21 * b1 + w22 * b2;
    float o1 = w00 * t1 + w01 * t2 + w02 * t3 + w10 * m1 + w11 * m2 + w12 * m3 +
               w20 * b1 + w21 * b2 + w22 * b3;
    float o2 = w00 * t2 + w01 * t3 + w02 * t4 + w10 * m2 + w11 * m3 + w12 * m4 +
               w20 * b2 + w21 * b3 + w22 * b4;
    float o3 = w00 * t3 + w01 * t4 + w02 * t5 + w10 * m3 + w11 * m4 + w12 * m5 +
               w20 * b3 + w21 * b4 + w22 * b5;
    sq += o0 * o0 + o1 * o1 + o2 * o2 + o3 * o3;
    bf16x4 h4, l4;
    __bf16 h0 = (__bf16)o0, h1 = (__bf16)o1, h2 = (__bf16)o2, h3 = (__bf16)o3;
    h4[0] = h0; h4[1] = h1; h4[2] = h2; h4[3] = h3;
    l4[0] = (__bf16)(o0 - (float)h0);
    l4[1] = (__bf16)(o1 - (float)h1);
    l4[2] = (__bf16)(o2 - (float)h2);
    l4[3] = (__bf16)(o3 - (float)h3);
    long off = obase + (y0 + i) * WDIM + xg * 4;
    *(bf16x4*)&dwh[off] = h4;
    *(bf16x4*)&dwl[off] = l4;
    lA = lB; rA = rB;
    lB = lC; rB = rC;
  }
  if (ch < 768) {
#pragma unroll
    for (int off = 32; off >= 1; off >>= 1) sq += __shfl_down(sq, off, 64);
    if ((tid & 63) == 0) {
      int b = b0 + bz;
      if (ch < 384)
        atomicAdd(qs + b * 384 + ch, sq);
      else
        atomicAdd(ks + b * 384 + (ch - 384), sq);
    }
  }
}

// ---------- gram_mfma: G[b,h] += Qd(48,P) x Kd(48,P)^T via 16x16x32 MFMA (split bf16) ----------
// Grid (32 px-chunks, 8 h, nbc), 256 thr = 4 waves; wave w owns px [pc*512 + w*128, +128).
// Trip-count-4 full unroll (load hoisting) + setprio around MFMA clusters (T5 regime).
__global__ __launch_bounds__(256) void gram_mfma(
    const __bf16* __restrict__ dwh, const __bf16* __restrict__ dwl,
    float* __restrict__ gram, int b0) {
  __shared__ float R[4][2304];
  const int tid = threadIdx.x, lane = tid & 63, wv = tid >> 6;
  const int pc = blockIdx.x, h = blockIdx.y, bz = blockIdx.z;
  const __bf16* Qh = dwh + ((long)bz * 1152 + h * 48) * HWN;
  const __bf16* Ql = dwl + ((long)bz * 1152 + h * 48) * HWN;
  const __bf16* Kh = dwh + ((long)bz * 1152 + 384 + h * 48) * HWN;
  const __bf16* Kl = dwl + ((long)bz * 1152 + 384 + h * 48) * HWN;
  const int fm = lane & 15;
  const int fk = (lane >> 4) << 3;
  floatx4 acc[3][3] = {};
  const int pstart = pc * 512 + wv * 128;
#pragma unroll
  for (int s = 0; s < 4; ++s) {
    const int p0 = pstart + s * 32;
    bf16x8 ah[3], al[3], bh[3], bl[3];
#pragma unroll
    for (int i = 0; i < 3; ++i) {
      const long ro = (long)(i * 16 + fm) * HWN + p0 + fk;
      ah[i] = *(const bf16x8*)(Qh + ro);
      al[i] = *(const bf16x8*)(Ql + ro);
      bh[i] = *(const bf16x8*)(Kh + ro);
      bl[i] = *(const bf16x8*)(Kl + ro);
    }
    __builtin_amdgcn_s_setprio(1);
#pragma unroll
    for (int i = 0; i < 3; ++i)
#pragma unroll
      for (int j = 0; j < 3; ++j) {
        acc[i][j] = __builtin_amdgcn_mfma_f32_16x16x32_bf16(ah[i], bh[j], acc[i][j], 0, 0, 0);
        acc[i][j] = __builtin_amdgcn_mfma_f32_16x16x32_bf16(al[i], bh[j], acc[i][j], 0, 0, 0);
        acc[i][j] = __builtin_amdgcn_mfma_f32_16x16x32_bf16(ah[i], bl[j], acc[i][j], 0, 0, 0);
      }
    __builtin_amdgcn_s_setprio(0);
  }
#pragma unroll
  for (int i = 0; i < 3; ++i)
#pragma unroll
    for (int j = 0; j < 3; ++j)
#pragma unroll
      for (int r = 0; r < 4; ++r)
        R[wv][(i * 16 + (lane >> 4) * 4 + r) * 48 + j * 16 + fm] = acc[i][j][r];
  __syncthreads();
  float* gb = gram + (long)((b0 + bz) * 8 + h) * 2304;
  for (int idx = tid; idx < 2304; idx += 256) {
    float s = R[0][idx] + R[1][idx] + R[2][idx] + R[3][idx];
    atomicAdd(gb + idx, s);
  }
}

// ---------- attn_M: normalize+top7+softmax then M = proj_w @ blockdiag(attn) ----------
__global__ __launch_bounds__(256) void attn_M(
    const float* __restrict__ gram, const float* __restrict__ qs, const float* __restrict__ ks,
    const float* __restrict__ temp, const float* __restrict__ pw,
    __bf16* __restrict__ Mh, __bf16* __restrict__ Ml, int b0) {
  const int z = blockIdx.x;
  const int b = b0 + (z >> 3), h = z & 7;
  __shared__ float kn[48];
  __shared__ float at[48][49];
  const int tid = threadIdx.x;
  if (tid < 48) kn[tid] = fmaxf(sqrtf(ks[b * 384 + h * 48 + tid]), 1e-12f);
  __syncthreads();
  if (tid < 48) {
    const int c = tid;
    float qn = fmaxf(sqrtf(qs[b * 384 + h * 48 + c]), 1e-12f);
    float tv = temp[h];
    const float* gr = gram + (long)(b * 8 + h) * 2304 + c * 48;
    float s[48];
#pragma unroll
    for (int d = 0; d < 48; ++d) s[d] = gr[d] / (qn * kn[d]) * tv;
    unsigned long long sel = 0ull;
    float m0 = 0.f;
    for (int it = 0; it < 7; ++it) {
      float mx = -3.0e38f;
      int mi = 0;
#pragma unroll
      for (int d = 0; d < 48; ++d) {
        bool taken = (sel >> d) & 1ull;
        if (!taken && s[d] > mx) { mx = s[d]; mi = d; }
      }
      sel |= (1ull << mi);
      if (it == 0) m0 = mx;
    }
    float sum = 0.f;
    float e[48];
#pragma unroll
    for (int d = 0; d < 48; ++d) {
      bool t = (sel >> d) & 1ull;
      float ev = t ? expf(s[d] - m0) : 0.f;
      e[d] = ev;
      sum += ev;
    }
    float inv = 1.f / sum;
#pragma unroll
    for (int d = 0; d < 48; ++d) at[c][d] = e[d] * inv;
  }
  __syncthreads();
  for (int idx = tid; idx < 384 * 48; idx += 256) {
    int o = idx / 48, d = idx % 48;
    const float* pr = pw + (long)o * 384 + h * 48;
    float acc = 0.f;
#pragma unroll
    for (int c = 0; c < 48; ++c) acc += pr[c] * at[c][d];
    long oi = ((long)b * 384 + o) * 384 + h * 48 + d;
    __bf16 hh = (__bf16)acc;
    Mh[oi] = hh;
    Ml[oi] = (__bf16)(acc - (float)hh);
  }
}

extern "C" void kernel_launch(void* const* d_in, const int* in_sizes, int n_in,
                              void* d_out, int out_size, void* d_ws, size_t ws_size,
                              hipStream_t stream) {
  const float* x = (const float*)d_in[0];       // (8,384,128,128)
  const float* qkv_w = (const float*)d_in[1];   // (1152,384)
  const float* dw_w = (const float*)d_in[2];    // (1152,1,3,3)
  const float* proj_w = (const float*)d_in[3];  // (384,384)
  const float* temp = (const float*)d_in[4];    // (8,)
  float* out = (float*)d_out;
  float* ws = (float*)d_ws;

  // ws layout (floats):
  float* gram = ws;                        // 147456
  float* qs = gram + 147456;               // 3072
  float* ks = qs + 3072;                   // 3072
  __bf16* Wh = (__bf16*)(ks + 3072);       // 442368 bf16
  __bf16* Wl = Wh + 442368;                // 442368 bf16
  __bf16* Mh = Wl + 442368;                // 8*147456 bf16
  __bf16* Ml = Mh + 1179648;               // 8*147456 bf16
  float* qkv1 = (float*)(Ml + 1179648);    // nb*1152*16384 f
  const long SMALLS = 1775616L;            // floats
  // per-batch: qkv1 fp32 (18874368) + dwh/dwl bf16 (18874368 f)
  const long PERB = 37748736L;
  long wsf = (long)(ws_size / 4);
  int nb = (int)((wsf - SMALLS) / PERB);
  if (nb < 1) nb = 1;
  if (nb > 8) nb = 8;
  __bf16* dwh = (__bf16*)(qkv1 + (long)nb * 18874368L);
  __bf16* dwl = dwh + (long)nb * 18874368L;

  hipMemsetAsync(gram, 0, (147456 + 3072 + 3072) * sizeof(float), stream);
  split_w<<<dim3((442368 + 255) / 256), 256, 0, stream>>>(qkv_w, Wh, Wl, 442368);

  for (int b0 = 0; b0 < 8; b0 += nb) {
    int nbc = (8 - b0 < nb) ? (8 - b0) : nb;
    // K1: qkv1 = W @ x[b]   (M=1152, K=384), split-bf16 MFMA (on-the-fly B split)
    gemm_mfma3<<<dim3(128, 9, nbc), 256, 0, stream>>>(
        Wh, Wl, x + (long)b0 * 6291456L, qkv1, 384, 0L, 6291456L, 18874368L);
    // dw all 1152 channels -> bf16 hi/lo, q/k sumsq fused (full-height burst version)
    dw_split<<<dim3(1152, nbc), 256, 0, stream>>>(qkv1, dw_w, dwh, dwl, qs, ks, b0);
    // gram via MFMA on split outputs (unrolled + setprio)
    gram_mfma<<<dim3(32, 8, nbc), 256, 0, stream>>>(dwh, dwl, gram, b0);
    // attn + M build (fused)
    attn_M<<<dim3(nbc * 8), 256, 0, stream>>>(gram, qs, ks, temp, proj_w, Mh, Ml, b0);
    // K5: out[b] = M_b @ v[b]   (M=384, K=384), pre-split bf16 B (v = dw channels 768..1151)
    gemm_bf3<<<dim3(128, 3, nbc), 256, 0, stream>>>(
        Mh + (long)b0 * 147456L, Ml + (long)b0 * 147456L,
        dwh + 768L * HWN, dwl + 768L * HWN,
        out + (long)b0 * 6291456L, 384, 147456L, 18874368L, 6291456L);
  }
}